// Round 19
// baseline (130.958 us; speedup 1.0000x reference)
//
#include <hip/hip_runtime.h>
#include <hip/hip_bf16.h>

#define NN 2048
#define LOG2E 1.4426950408889634f

typedef unsigned int u32;
typedef unsigned short u16;
typedef unsigned char u8;

typedef __attribute__((ext_vector_type(8))) short short8;
typedef __attribute__((ext_vector_type(4))) float f32x4;

__device__ __forceinline__ u16 f2bf(float f){
  __hip_bfloat16 h = __float2bfloat16(f);
  return *reinterpret_cast<u16*>(&h);
}
__device__ __forceinline__ float bf1(u16 u){ return __uint_as_float(((u32)u) << 16); }
__device__ __forceinline__ float bflo(u32 u){ return __uint_as_float(u << 16); }
__device__ __forceinline__ float bfhi(u32 u){ return __uint_as_float(u & 0xffff0000u); }
__device__ __forceinline__ u32 pack2(float a, float b){
  return (u32)f2bf(a) | ((u32)f2bf(b) << 16);
}
__device__ __forceinline__ void gload16(const void* g, void* l){
  __builtin_amdgcn_global_load_lds((const __attribute__((address_space(1))) u32*)g,
                                   (__attribute__((address_space(3))) u32*)l, 16, 0, 0);
}

// Collapse attn_mask (B,R,N,N) int32 + key_padding (B,N) int32 into a combo byte
// per (b,n,m): bit r = attn_mask[b][r][n][m], bit 3 = key_padding[b][m].
__global__ __launch_bounds__(256)
void prep_k(const int* __restrict__ am, const int* __restrict__ kp,
            u8* __restrict__ cmb)
{
  const size_t tid  = (size_t)blockIdx.x * 256 + threadIdx.x;
  const size_t base = tid * 4;
  const int row = (int)(base >> 11);            // b*2048 + n
  const int m0  = (int)(base & 2047);
  const int b = row >> 11, n = row & 2047;
  const size_t e0 = (((size_t)(b*3) * NN) + n) * NN + m0;
  const int4 a0 = *reinterpret_cast<const int4*>(am + e0);
  const int4 a1 = *reinterpret_cast<const int4*>(am + e0 + (size_t)NN*NN);
  const int4 a2 = *reinterpret_cast<const int4*>(am + e0 + 2*(size_t)NN*NN);
  const int4 kv = *reinterpret_cast<const int4*>(kp + (size_t)b*NN + m0);
  const int a0v[4] = {a0.x,a0.y,a0.z,a0.w};
  const int a1v[4] = {a1.x,a1.y,a1.z,a1.w};
  const int a2v[4] = {a2.x,a2.y,a2.z,a2.w};
  const int kvv[4] = {kv.x,kv.y,kv.z,kv.w};
  uchar4 out;
  u8* o = (u8*)&out;
  #pragma unroll
  for (int i = 0; i < 4; ++i)
    o[i] = (u8)((a0v[i]?1:0) | (a1v[i]?2:0) | (a2v[i]?4:0) | (kvv[i]?8:0));
  *reinterpret_cast<uchar4*>(cmb + base) = out;
}

// Transpose 4 W f32 [512][512] -> bf16 W^T [n][k]. grid (16,16,4).
__global__ __launch_bounds__(256)
void trw4_k(const float* __restrict__ W0, const float* __restrict__ W1,
            const float* __restrict__ W2, const float* __restrict__ W3,
            u16* __restrict__ WT)
{
  __shared__ float tile[32][33];
  const int zz = blockIdx.z;
  const float* W = (zz == 0) ? W0 : (zz == 1) ? W1 : (zz == 2) ? W2 : W3;
  u16* dst = WT + (size_t)zz * 262144;
  const int t = threadIdx.x;
  const int k0 = blockIdx.x * 32, n0 = blockIdx.y * 32;
  const int c = t & 31, r = t >> 5;
  #pragma unroll
  for (int i = 0; i < 4; ++i)
    tile[r + 8*i][c] = W[(size_t)(k0 + r + 8*i) * 512 + n0 + c];
  __syncthreads();
  #pragma unroll
  for (int i = 0; i < 4; ++i)
    dst[(size_t)(n0 + r + 8*i) * 512 + k0 + c] = f2bf(tile[c][r + 8*i]);
}

// Double-buffered MFMA GEMM core: C[64 x BN block] = (A @ W^T + bias)*scale.
template<int BN, bool SCATTER, bool ABF16, bool OUTF32>
__device__ __forceinline__
void gemm_core(const void* __restrict__ Av, const u16* __restrict__ WT,
               const float* __restrict__ bias, void* __restrict__ Cd,
               float scale, int m0, int n0)
{
  constexpr int NI  = BN / 64;
  constexpr int WNL = BN / 32;
  __shared__ u16 As[2][64*64];
  __shared__ u16 Ws[2][BN*64];

  const int t = threadIdx.x;
  const int lane = t & 63;
  const int w = t >> 6;
  const int g = lane >> 4, r15 = lane & 15;
  const int wn = w * (BN/4);

  const int arow = t >> 2, akc = (t & 3) * 16, as0 = (t & 3) * 2;
  const int wrn = (BN==128) ? (t>>1) : (t>>2);
  const int wkc = (BN==128) ? ((t&1)*32) : ((t&3)*16);
  const int wsb = (BN==128) ? ((t&1)*4)  : ((t&3)*2);

  uint4  war[WNL];
  uint4  aab[2];
  float4 aaf[4];

  auto loadA = [&](int k0){
    if constexpr (ABF16) {
      const u16* A = (const u16*)Av;
      aab[0] = *reinterpret_cast<const uint4*>(A + (size_t)(m0+arow)*512 + k0 + akc);
      aab[1] = *reinterpret_cast<const uint4*>(A + (size_t)(m0+arow)*512 + k0 + akc + 8);
    } else {
      const float* A = (const float*)Av;
      #pragma unroll
      for (int q = 0; q < 4; ++q)
        aaf[q] = *reinterpret_cast<const float4*>(A + (size_t)(m0+arow)*512 + k0 + akc + 4*q);
    }
  };
  auto loadW = [&](int k0){
    #pragma unroll
    for (int i = 0; i < WNL; ++i)
      war[i] = *reinterpret_cast<const uint4*>(WT + (size_t)(n0+wrn)*512 + k0 + wkc + 8*i);
  };
  auto writeA = [&](int bf){
    uint4 v0, v1;
    if constexpr (ABF16) { v0 = aab[0]; v1 = aab[1]; }
    else {
      v0.x = pack2(aaf[0].x, aaf[0].y); v0.y = pack2(aaf[0].z, aaf[0].w);
      v0.z = pack2(aaf[1].x, aaf[1].y); v0.w = pack2(aaf[1].z, aaf[1].w);
      v1.x = pack2(aaf[2].x, aaf[2].y); v1.y = pack2(aaf[2].z, aaf[2].w);
      v1.z = pack2(aaf[3].x, aaf[3].y); v1.w = pack2(aaf[3].z, aaf[3].w);
    }
    *reinterpret_cast<uint4*>(&As[bf][arow*64 + (((as0  ) ^ (arow&7)) << 3)]) = v0;
    *reinterpret_cast<uint4*>(&As[bf][arow*64 + (((as0+1) ^ (arow&7)) << 3)]) = v1;
  };
  auto writeW = [&](int bf){
    #pragma unroll
    for (int i = 0; i < WNL; ++i)
      *reinterpret_cast<uint4*>(&Ws[bf][wrn*64 + (((wsb+i) ^ (wrn&7)) << 3)]) = war[i];
  };

  const f32x4 fz = {0.f,0.f,0.f,0.f};
  f32x4 acc[4][NI];
  #pragma unroll
  for (int mi = 0; mi < 4; ++mi)
    #pragma unroll
    for (int ni = 0; ni < NI; ++ni) acc[mi][ni] = fz;

  loadA(0); loadW(0);
  writeA(0); writeW(0);
  __syncthreads();

  for (int kt = 0; kt < 8; ++kt) {
    const int cur = kt & 1;
    if (kt < 7) { loadA((kt+1)*64); loadW((kt+1)*64); }
    #pragma unroll
    for (int ks = 0; ks < 2; ++ks) {
      short8 bfr[NI], afr[4];
      #pragma unroll
      for (int ni = 0; ni < NI; ++ni) {
        const int n = wn + 16*ni + r15;
        bfr[ni] = *reinterpret_cast<const short8*>(&Ws[cur][n*64 + (((ks*4+g) ^ (n&7)) << 3)]);
      }
      #pragma unroll
      for (int mi = 0; mi < 4; ++mi) {
        const int m = 16*mi + r15;
        afr[mi] = *reinterpret_cast<const short8*>(&As[cur][m*64 + (((ks*4+g) ^ (m&7)) << 3)]);
      }
      #pragma unroll
      for (int mi = 0; mi < 4; ++mi)
        #pragma unroll
        for (int ni = 0; ni < NI; ++ni)
          acc[mi][ni] = __builtin_amdgcn_mfma_f32_16x16x32_bf16(afr[mi], bfr[ni], acc[mi][ni], 0, 0, 0);
    }
    if (kt < 7) { writeA(cur^1); writeW(cur^1); }
    __syncthreads();
  }

  float bia[NI];
  #pragma unroll
  for (int ni = 0; ni < NI; ++ni) bia[ni] = bias[n0 + wn + 16*ni + r15];
  #pragma unroll
  for (int mi = 0; mi < 4; ++mi) {
    #pragma unroll
    for (int ni = 0; ni < NI; ++ni) {
      #pragma unroll
      for (int j = 0; j < 4; ++j) {
        const int row = m0 + 16*mi + 4*g + j;
        const int col = n0 + wn + 16*ni + r15;
        const float v = (acc[mi][ni][j] + bia[ni]) * scale;
        if constexpr (SCATTER) {
          const int bb = row & 1, ntok = row >> 1;
          const int h = col >> 6, c = col & 63;
          ((u16*)Cd)[(((size_t)(bb*8 + h) * NN + ntok) * 64) + c] = f2bf(v);
        } else if constexpr (OUTF32) {
          ((float*)Cd)[(size_t)row * 512 + col] = v;
        } else {
          ((u16*)Cd)[(size_t)row * 512 + col] = f2bf(v);
        }
      }
    }
  }
}

// Fused QKV projections: grid (64, 4, 3), BN=128 (round-17 best).
__global__ __launch_bounds__(256)
void gemm_qkv(const float* __restrict__ x0, const float* __restrict__ x1,
              const float* __restrict__ x2, const u16* __restrict__ WT3,
              const float* __restrict__ b0, const float* __restrict__ b1,
              const float* __restrict__ b2, u16* __restrict__ dst, float qscale)
{
  const int z = blockIdx.z;
  const float* A    = (z == 0) ? x0 : (z == 1) ? x1 : x2;
  const float* bias = (z == 0) ? b0 : (z == 1) ? b1 : b2;
  gemm_core<128, true, false, false>(A, WT3 + (size_t)z*262144, bias,
                                     dst + (size_t)z*2097152,
                                     (z == 0) ? qscale : 1.0f,
                                     blockIdx.x*64, blockIdx.y*128);
}

// Output projection with fused split-K merge: A[row][k] is reconstructed from
// bf16 partials + (m,l) on the fly (replaces the combine_k dispatch + Ob trip).
// grid (64, 8). BN=64.
__global__ __launch_bounds__(256)
void gemm_wo_merge(const u16* __restrict__ Opart, const float2* __restrict__ Ml,
                   int nsplit, const u16* __restrict__ WT,
                   const float* __restrict__ bias, float* __restrict__ out)
{
  __shared__ u16 As[2][64*64];
  __shared__ u16 Ws[2][64*64];

  const int t = threadIdx.x;
  const int lane = t & 63;
  const int w = t >> 6;
  const int g = lane >> 4, r15 = lane & 15;
  const int m0 = blockIdx.x * 64;
  const int n0 = blockIdx.y * 64;
  const int wn = w * 16;
  const float NEGINF = -__builtin_inff();

  const int arow = t >> 2, akc = (t & 3) * 16, as0 = (t & 3) * 2;
  const int wrn = t >> 2, wkc = (t & 3) * 16, wsb = (t & 3) * 2;

  uint4 war[2];
  uint4 aab[2];

  auto loadA = [&](int k0){
    // merged A value for token-row (m0+arow), channels k0+akc .. +15 (one head)
    const int row = m0 + arow;
    const int q = row >> 1, bb = row & 1;
    const int bh = bb*8 + (k0 >> 6);
    const int c0 = akc;
    float M = NEGINF;
    for (int s = 0; s < nsplit; ++s)
      M = fmaxf(M, Ml[((size_t)(s*16 + bh)) * NN + q].x);
    float num[16];
    #pragma unroll
    for (int j = 0; j < 16; ++j) num[j] = 0.f;
    float den = 0.f;
    for (int s = 0; s < nsplit; ++s) {
      const float2 ml = Ml[((size_t)(s*16 + bh)) * NN + q];
      const float wsc = (ml.x == NEGINF) ? 0.f : exp2f(ml.x - M);
      den += wsc * ml.y;
      const u16* pr = Opart + (((size_t)(s*16 + bh)) * NN + q) * 64 + c0;
      const uint4 p0 = *reinterpret_cast<const uint4*>(pr);
      const uint4 p1 = *reinterpret_cast<const uint4*>(pr + 8);
      const u32 pw[8] = {p0.x,p0.y,p0.z,p0.w,p1.x,p1.y,p1.z,p1.w};
      #pragma unroll
      for (int j = 0; j < 8; ++j) {
        num[2*j]   = fmaf(wsc, bflo(pw[j]), num[2*j]);
        num[2*j+1] = fmaf(wsc, bfhi(pw[j]), num[2*j+1]);
      }
    }
    const float rinv = (den > 0.f) ? 1.f/den : 0.f;
    u32* aw = reinterpret_cast<u32*>(&aab[0]);
    #pragma unroll
    for (int j = 0; j < 8; ++j)
      aw[j] = pack2(num[2*j]*rinv, num[2*j+1]*rinv);
  };
  auto loadW = [&](int k0){
    #pragma unroll
    for (int i = 0; i < 2; ++i)
      war[i] = *reinterpret_cast<const uint4*>(WT + (size_t)(n0+wrn)*512 + k0 + wkc + 8*i);
  };
  auto writeA = [&](int bf){
    *reinterpret_cast<uint4*>(&As[bf][arow*64 + (((as0  ) ^ (arow&7)) << 3)]) = aab[0];
    *reinterpret_cast<uint4*>(&As[bf][arow*64 + (((as0+1) ^ (arow&7)) << 3)]) = aab[1];
  };
  auto writeW = [&](int bf){
    #pragma unroll
    for (int i = 0; i < 2; ++i)
      *reinterpret_cast<uint4*>(&Ws[bf][wrn*64 + (((wsb+i) ^ (wrn&7)) << 3)]) = war[i];
  };

  const f32x4 fz = {0.f,0.f,0.f,0.f};
  f32x4 acc[4];
  #pragma unroll
  for (int mi = 0; mi < 4; ++mi) acc[mi] = fz;

  loadA(0); loadW(0);
  writeA(0); writeW(0);
  __syncthreads();

  for (int kt = 0; kt < 8; ++kt) {
    const int cur = kt & 1;
    if (kt < 7) { loadA((kt+1)*64); loadW((kt+1)*64); }
    #pragma unroll
    for (int ks = 0; ks < 2; ++ks) {
      short8 bfr, afr[4];
      const int n = wn + r15;
      bfr = *reinterpret_cast<const short8*>(&Ws[cur][n*64 + (((ks*4+g) ^ (n&7)) << 3)]);
      #pragma unroll
      for (int mi = 0; mi < 4; ++mi) {
        const int m = 16*mi + r15;
        afr[mi] = *reinterpret_cast<const short8*>(&As[cur][m*64 + (((ks*4+g) ^ (m&7)) << 3)]);
      }
      #pragma unroll
      for (int mi = 0; mi < 4; ++mi)
        acc[mi] = __builtin_amdgcn_mfma_f32_16x16x32_bf16(afr[mi], bfr, acc[mi], 0, 0, 0);
    }
    if (kt < 7) { writeA(cur^1); writeW(cur^1); }
    __syncthreads();
  }

  const float bia = bias[n0 + wn + r15];
  #pragma unroll
  for (int mi = 0; mi < 4; ++mi) {
    #pragma unroll
    for (int j = 0; j < 4; ++j) {
      const int row = m0 + 16*mi + 4*g + j;
      const int col = n0 + wn + r15;
      out[(size_t)row * 512 + col] = acc[mi][j] + bia;
    }
  }
}

// MFMA flash attention (round-17 exact): 8 waves / 128 q, split-K, exp2 domain,
// 1 barrier/tile, K via global_load_lds (pre-swizzled source), Ps-LDS P path,
// defer-max, bf16 partials, setprio around MFMA clusters.
__global__ __launch_bounds__(512)
void attn_mfma(const u16* __restrict__ Q, const u16* __restrict__ K,
               const u16* __restrict__ V, const u8* __restrict__ cmb,
               const float* __restrict__ mw, u16* __restrict__ O,
               u16* __restrict__ Opart, float2* __restrict__ Ml, int kspan)
{
  __shared__ u16 Ks[2][64*64];
  __shared__ u16 Vs[2][64*64];
  __shared__ u16 Ps[8][16*64];
  __shared__ float lut[16];

  const int t = threadIdx.x;
  const int lane = t & 63;
  const int w = t >> 6;
  const int g = lane >> 4;
  const int r15 = lane & 15;
  const int bh = blockIdx.y;
  const int z = blockIdx.z;
  const int b = bh >> 3, h = bh & 7;
  const int n0 = blockIdx.x * 128;
  const int nq = n0 + w*16 + r15;
  const int k_beg = z * kspan;
  const float NEGINF = -__builtin_inff();

  if (t < 16) {
    const float mw0 = mw[h*4+0], mw1 = mw[h*4+1], mw2 = mw[h*4+2];
    const float msc = mw[h*4+3];
    const float mxw = fmaxf(mw0, fmaxf(mw1, mw2));
    const float e0 = __expf(mw0-mxw), e1 = __expf(mw1-mxw), e2 = __expf(mw2-mxw);
    const float inv = msc / (e0+e1+e2);
    float v = ((t & 1) ? 0.f : e0*inv) + ((t & 2) ? 0.f : e1*inv)
            + ((t & 4) ? 0.f : e2*inv);
    lut[t] = (t & 8) ? NEGINF : v * LOG2E;
  }

  const u16* qrow = Q + ((size_t)bh*NN + nq)*64;
  const short8 bq0 = *reinterpret_cast<const short8*>(qrow + 8*g);
  const short8 bq1 = *reinterpret_cast<const short8*>(qrow + 32 + 8*g);

  const u8* crow = cmb + ((size_t)(b*NN + nq))*NN;
  const u16* Kbase = K + (size_t)bh*NN*64;
  const u16* Vbase = V + (size_t)bh*NN*64;

  float m_run = NEGINF, l_run = 0.f;
  const f32x4 fz = {0.f, 0.f, 0.f, 0.f};
  f32x4 oacc[4] = {fz, fz, fz, fz};

  const int sm  = t >> 3;
  const int ssl = t & 7;
  const int kcol = (ssl ^ (sm & 7)) * 8;
  const int sc0 = (t & 7) * 8;

  uint4 vreg;
  auto gloadK = [&](int m0, int bf){
    gload16(Kbase + (size_t)(m0 + sm)*64 + kcol, &Ks[bf][w*512 + (lane << 3)]);
  };
  auto loadV = [&](int m0){
    vreg = *reinterpret_cast<const uint4*>(Vbase + (size_t)(m0 + sm)*64 + sc0);
  };
  auto writeV = [&](int bf){
    u16 e[8];
    e[0]=vreg.x&0xffff; e[1]=vreg.x>>16; e[2]=vreg.y&0xffff; e[3]=vreg.y>>16;
    e[4]=vreg.z&0xffff; e[5]=vreg.z>>16; e[6]=vreg.w&0xffff; e[7]=vreg.w>>16;
    #pragma unroll
    for (int i = 0; i < 8; ++i) {
      const int c = sc0 + i;
      Vs[bf][c*64 + ((((sm>>3) ^ (c&7) ^ (c>>3)) << 3) | (sm & 7))] = e[i];
    }
  };

  const int ntiles = kspan >> 6;
  gloadK(k_beg, 0);
  loadV(k_beg);
  writeV(0);
  __syncthreads();

  for (int it = 0; it < ntiles; ++it) {
    const int cur = it & 1;
    const int m0 = k_beg + it * 64;
    const bool more = (it + 1 < ntiles);
    if (more) { gloadK(m0 + 64, cur ^ 1); loadV(m0 + 64); }

    float sv[4][4];
    __builtin_amdgcn_s_setprio(1);
    #pragma unroll
    for (int kt = 0; kt < 4; ++kt) {
      const int key = 16*kt + r15;
      const short8 a0 = *reinterpret_cast<const short8*>(&Ks[cur][key*64 + (((g  ) ^ (key&7)) << 3)]);
      const short8 a1 = *reinterpret_cast<const short8*>(&Ks[cur][key*64 + (((g+4) ^ (key&7)) << 3)]);
      f32x4 s = fz;
      s = __builtin_amdgcn_mfma_f32_16x16x32_bf16(a0, bq0, s, 0, 0, 0);
      s = __builtin_amdgcn_mfma_f32_16x16x32_bf16(a1, bq1, s, 0, 0, 0);
      const u32 cw = *reinterpret_cast<const u32*>(crow + m0 + 16*kt + 4*g);
      #pragma unroll
      for (int j = 0; j < 4; ++j)
        sv[kt][j] = s[j] + lut[(cw >> (8*j)) & 0xfu];
    }
    __builtin_amdgcn_s_setprio(0);
    float pmax = NEGINF;
    #pragma unroll
    for (int kt = 0; kt < 4; ++kt)
      #pragma unroll
      for (int j = 0; j < 4; ++j) pmax = fmaxf(pmax, sv[kt][j]);
    float tmax = pmax;
    tmax = fmaxf(tmax, __shfl_xor(tmax, 16));
    tmax = fmaxf(tmax, __shfl_xor(tmax, 32));

    const bool skip = __all((m_run != NEGINF) && (tmax <= m_run + 10.0f));
    float nm = m_run, sc = 1.0f;
    if (!skip) {
      nm = fmaxf(m_run, tmax);
      if (nm != NEGINF) { sc = exp2f(m_run - nm); m_run = nm; }
      #pragma unroll
      for (int ct = 0; ct < 4; ++ct) oacc[ct] *= sc;
    }

    float psum = 0.f;
    #pragma unroll
    for (int kt = 0; kt < 4; ++kt) {
      float p[4];
      #pragma unroll
      for (int j = 0; j < 4; ++j) {
        p[j] = (nm == NEGINF) ? 0.f : exp2f(sv[kt][j] - nm);
        psum += p[j];
      }
      const int slot = 2*kt + (g >> 1);
      const int off  = 4 * (g & 1);
      *reinterpret_cast<ushort4*>(&Ps[w][r15*64 + ((slot ^ (r15 & 7)) << 3) + off]) =
        make_ushort4(f2bf(p[0]), f2bf(p[1]), f2bf(p[2]), f2bf(p[3]));
    }
    psum += __shfl_xor(psum, 16);
    psum += __shfl_xor(psum, 32);
    l_run = l_run * sc + psum;

    const short8 bp0 = *reinterpret_cast<const short8*>(&Ps[w][r15*64 + (((g  ) ^ (r15 & 7)) << 3)]);
    const short8 bp1 = *reinterpret_cast<const short8*>(&Ps[w][r15*64 + (((g+4) ^ (r15 & 7)) << 3)]);
    __builtin_amdgcn_s_setprio(1);
    #pragma unroll
    for (int ct = 0; ct < 4; ++ct) {
      const int c = 16*ct + r15;
      const short8 av0 = *reinterpret_cast<const short8*>(
        &Vs[cur][c*64 + ((((g  ) ^ (c&7) ^ (c>>3))) << 3)]);
      const short8 av1 = *reinterpret_cast<const short8*>(
        &Vs[cur][c*64 + ((((g+4) ^ (c&7) ^ (c>>3))) << 3)]);
      oacc[ct] = __builtin_amdgcn_mfma_f32_16x16x32_bf16(av0, bp0, oacc[ct], 0, 0, 0);
      oacc[ct] = __builtin_amdgcn_mfma_f32_16x16x32_bf16(av1, bp1, oacc[ct], 0, 0, 0);
    }
    __builtin_amdgcn_s_setprio(0);

    if (more) writeV(cur ^ 1);
    __syncthreads();
  }

  if (Opart) {
    u16* orow = Opart + (((size_t)(z*16 + bh)) * NN + nq) * 64;
    #pragma unroll
    for (int ct = 0; ct < 4; ++ct)
      *reinterpret_cast<ushort4*>(orow + 16*ct + 4*g) =
        make_ushort4(f2bf(oacc[ct][0]), f2bf(oacc[ct][1]),
                     f2bf(oacc[ct][2]), f2bf(oacc[ct][3]));
    if (g == 0)
      Ml[((size_t)(z*16 + bh)) * NN + nq] = make_float2(m_run, l_run);
  } else {
    const float rinv = 1.f / l_run;
    #pragma unroll
    for (int ct = 0; ct < 4; ++ct) {
      u16* dst = O + ((size_t)(nq*2 + b))*512 + h*64 + 16*ct + 4*g;
      *reinterpret_cast<ushort4*>(dst) =
        make_ushort4(f2bf(oacc[ct][0]*rinv), f2bf(oacc[ct][1]*rinv),
                     f2bf(oacc[ct][2]*rinv), f2bf(oacc[ct][3]*rinv));
    }
  }
}

// Fallback merge (no-split path only).
__global__ __launch_bounds__(256)
void combine_k(const u16* __restrict__ Opart, const float2* __restrict__ Ml,
               u16* __restrict__ Ob, int nsplit)
{
  const int t = threadIdx.x;
  const int lane = t & 63, w = t >> 6;
  const int q = blockIdx.x * 4 + w;
  const int bh = blockIdx.y;
  const int b = bh >> 3, h = bh & 7;

  float M = -__builtin_inff();
  for (int s = 0; s < nsplit; ++s)
    M = fmaxf(M, Ml[((size_t)(s*16 + bh)) * NN + q].x);

  float num = 0.f, den = 0.f;
  for (int s = 0; s < nsplit; ++s) {
    const float2 ml = Ml[((size_t)(s*16 + bh)) * NN + q];
    const float ws = (ml.x == -__builtin_inff()) ? 0.f : exp2f(ml.x - M);
    den += ws * ml.y;
    num += ws * bf1(Opart[(((size_t)(s*16 + bh)) * NN + q) * 64 + lane]);
  }
  const float r = (den > 0.f) ? num / den : 0.f;
  Ob[((size_t)(q*2 + b)) * 512 + h*64 + lane] = f2bf(r);
}

// Fallback Wo GEMM reading bf16 Ob (no-split path only).
__global__ __launch_bounds__(256)
void gemm_wo(const u16* __restrict__ Ob, const u16* __restrict__ WT,
             const float* __restrict__ bias, float* __restrict__ out)
{
  gemm_core<64, false, true, true>(Ob, WT, bias, out, 1.0f,
                                   blockIdx.x*64, blockIdx.y*64);
}

extern "C" void kernel_launch(void* const* d_in, const int* in_sizes, int n_in,
                              void* d_out, int out_size, void* d_ws, size_t ws_size,
                              hipStream_t stream)
{
  const float* xq = (const float*)d_in[0];
  const float* xk = (const float*)d_in[1];
  const float* xv = (const float*)d_in[2];
  const int*   am = (const int*)d_in[3];
  const int*   kp = (const int*)d_in[4];
  const float* Wq = (const float*)d_in[5];
  const float* bq = (const float*)d_in[6];
  const float* Wk = (const float*)d_in[7];
  const float* bk = (const float*)d_in[8];
  const float* Wv = (const float*)d_in[9];
  const float* bv = (const float*)d_in[10];
  const float* Wo = (const float*)d_in[11];
  const float* bo = (const float*)d_in[12];
  const float* mw = (const float*)d_in[13];

  u16* Qb = (u16*)d_ws;                       // [16][2048][64] bf16, 4 MB (x3 = QKV)
  u16* Kb = Qb + (size_t)16*NN*64;
  u16* Vb = Kb + (size_t)16*NN*64;
  u16* Ob = Vb + (size_t)16*NN*64;            // [4096][512] bf16, 4 MB (fallback only)
  u8*  cmb = (u8*)(Ob + (size_t)4096*512);    // [2][2048][2048] bytes, 8 MB
  u8*  R   = cmb + (size_t)2*NN*NN;           // scratch region

  u16* Opart = (u16*)R;                       // split-K bf16 partials (<= 17.75 MB @ 4)
  const size_t base_bytes = (size_t)(R - (u8*)d_ws);
  int nsplit = 1;
  for (int s = 4; s >= 1; s >>= 1) {
    const size_t need = base_bytes + (size_t)s * 16 * NN * (64*2 + 8);
    if (need <= ws_size) { nsplit = s; break; }
  }
  float2* Ml = (float2*)(Opart + (size_t)nsplit * 16 * NN * 64);
  const bool split = (base_bytes + (size_t)16*NN*(64*2+8) <= ws_size);

  u16* WT4 = (u16*)(R + (size_t)18*1024*1024);
  const bool wt4_ok = (base_bytes + (size_t)18*1024*1024 + 4*262144*2 <= ws_size);
  u16* WT3 = wt4_ok ? WT4 : (u16*)R;
  u16* WTo = wt4_ok ? (WT4 + 3*262144) : Qb;

  prep_k<<<(2*NN*NN/4 + 255)/256, 256, 0, stream>>>(am, kp, cmb);

  const float qscale = 0.125f * LOG2E;
  trw4_k<<<dim3(16, 16, wt4_ok ? 4 : 3), 256, 0, stream>>>(Wq, Wk, Wv, Wo,
                                                           wt4_ok ? WT4 : WT3);
  gemm_qkv<<<dim3(64, 4, 3), 256, 0, stream>>>(xq, xk, xv, WT3, bq, bk, bv, Qb, qscale);

  if (split && wt4_ok) {
    attn_mfma<<<dim3(16, 16, nsplit), 512, 0, stream>>>(Qb, Kb, Vb, cmb, mw, Ob,
                                                        Opart, Ml, NN / nsplit);
    gemm_wo_merge<<<dim3(64, 8), 256, 0, stream>>>(Opart, Ml, nsplit, WTo, bo,
                                                   (float*)d_out);
  } else if (split) {
    attn_mfma<<<dim3(16, 16, nsplit), 512, 0, stream>>>(Qb, Kb, Vb, cmb, mw, Ob,
                                                        Opart, Ml, NN / nsplit);
    combine_k<<<dim3(NN/4, 16), 256, 0, stream>>>(Opart, Ml, Ob, nsplit);
    gemm_wo<<<dim3(64, 8), 256, 0, stream>>>(Ob, WTo, bo, (float*)d_out);
  } else {
    attn_mfma<<<dim3(16, 16, 1), 512, 0, stream>>>(Qb, Kb, Vb, cmb, mw, Ob,
                                                   nullptr, nullptr, NN);
    gemm_wo<<<dim3(64, 8), 256, 0, stream>>>(Ob, WTo, bo, (float*)d_out);
  }
}

// Round 20
// 121.462 us; speedup vs baseline: 1.0782x; 1.0782x over previous
//
#include <hip/hip_runtime.h>
#include <hip/hip_bf16.h>

#define NN 2048
#define LOG2E 1.4426950408889634f

typedef unsigned int u32;
typedef unsigned short u16;
typedef unsigned char u8;

typedef __attribute__((ext_vector_type(8))) short short8;
typedef __attribute__((ext_vector_type(4))) float f32x4;

__device__ __forceinline__ u16 f2bf(float f){
  __hip_bfloat16 h = __float2bfloat16(f);
  return *reinterpret_cast<u16*>(&h);
}
__device__ __forceinline__ float bf1(u16 u){ return __uint_as_float(((u32)u) << 16); }
__device__ __forceinline__ u32 pack2(float a, float b){
  return (u32)f2bf(a) | ((u32)f2bf(b) << 16);
}
__device__ __forceinline__ void gload16(const void* g, void* l){
  __builtin_amdgcn_global_load_lds((const __attribute__((address_space(1))) u32*)g,
                                   (__attribute__((address_space(3))) u32*)l, 16, 0, 0);
}

// Collapse attn_mask (B,R,N,N) int32 + key_padding (B,N) int32 into a combo byte
// per (b,n,m): bit r = attn_mask[b][r][n][m], bit 3 = key_padding[b][m].
__global__ __launch_bounds__(256)
void prep_k(const int* __restrict__ am, const int* __restrict__ kp,
            u8* __restrict__ cmb)
{
  const size_t tid  = (size_t)blockIdx.x * 256 + threadIdx.x;
  const size_t base = tid * 4;
  const int row = (int)(base >> 11);            // b*2048 + n
  const int m0  = (int)(base & 2047);
  const int b = row >> 11, n = row & 2047;
  const size_t e0 = (((size_t)(b*3) * NN) + n) * NN + m0;
  const int4 a0 = *reinterpret_cast<const int4*>(am + e0);
  const int4 a1 = *reinterpret_cast<const int4*>(am + e0 + (size_t)NN*NN);
  const int4 a2 = *reinterpret_cast<const int4*>(am + e0 + 2*(size_t)NN*NN);
  const int4 kv = *reinterpret_cast<const int4*>(kp + (size_t)b*NN + m0);
  const int a0v[4] = {a0.x,a0.y,a0.z,a0.w};
  const int a1v[4] = {a1.x,a1.y,a1.z,a1.w};
  const int a2v[4] = {a2.x,a2.y,a2.z,a2.w};
  const int kvv[4] = {kv.x,kv.y,kv.z,kv.w};
  uchar4 out;
  u8* o = (u8*)&out;
  #pragma unroll
  for (int i = 0; i < 4; ++i)
    o[i] = (u8)((a0v[i]?1:0) | (a1v[i]?2:0) | (a2v[i]?4:0) | (kvv[i]?8:0));
  *reinterpret_cast<uchar4*>(cmb + base) = out;
}

// Transpose 4 W f32 [512][512] -> bf16 W^T [n][k]. grid (16,16,4).
__global__ __launch_bounds__(256)
void trw4_k(const float* __restrict__ W0, const float* __restrict__ W1,
            const float* __restrict__ W2, const float* __restrict__ W3,
            u16* __restrict__ WT)
{
  __shared__ float tile[32][33];
  const int zz = blockIdx.z;
  const float* W = (zz == 0) ? W0 : (zz == 1) ? W1 : (zz == 2) ? W2 : W3;
  u16* dst = WT + (size_t)zz * 262144;
  const int t = threadIdx.x;
  const int k0 = blockIdx.x * 32, n0 = blockIdx.y * 32;
  const int c = t & 31, r = t >> 5;
  #pragma unroll
  for (int i = 0; i < 4; ++i)
    tile[r + 8*i][c] = W[(size_t)(k0 + r + 8*i) * 512 + n0 + c];
  __syncthreads();
  #pragma unroll
  for (int i = 0; i < 4; ++i)
    dst[(size_t)(n0 + r + 8*i) * 512 + k0 + c] = f2bf(tile[c][r + 8*i]);
}

// Single-W transpose (fallback path only).
__global__ __launch_bounds__(256)
void trw_k(const float* __restrict__ W, u16* __restrict__ WT)
{
  __shared__ float tile[32][33];
  const int t = threadIdx.x;
  const int k0 = blockIdx.x * 32, n0 = blockIdx.y * 32;
  const int c = t & 31, r = t >> 5;
  #pragma unroll
  for (int i = 0; i < 4; ++i)
    tile[r + 8*i][c] = W[(size_t)(k0 + r + 8*i) * 512 + n0 + c];
  __syncthreads();
  #pragma unroll
  for (int i = 0; i < 4; ++i)
    WT[(size_t)(n0 + r + 8*i) * 512 + k0 + c] = f2bf(tile[c][r + 8*i]);
}

// Double-buffered MFMA GEMM core: C[64 x BN block] = (A @ W^T + bias)*scale.
template<int BN, bool SCATTER, bool ABF16, bool OUTF32>
__device__ __forceinline__
void gemm_core(const void* __restrict__ Av, const u16* __restrict__ WT,
               const float* __restrict__ bias, void* __restrict__ Cd,
               float scale, int m0, int n0)
{
  constexpr int NI  = BN / 64;
  constexpr int WNL = BN / 32;
  __shared__ u16 As[2][64*64];
  __shared__ u16 Ws[2][BN*64];

  const int t = threadIdx.x;
  const int lane = t & 63;
  const int w = t >> 6;
  const int g = lane >> 4, r15 = lane & 15;
  const int wn = w * (BN/4);

  const int arow = t >> 2, akc = (t & 3) * 16, as0 = (t & 3) * 2;
  const int wrn = (BN==128) ? (t>>1) : (t>>2);
  const int wkc = (BN==128) ? ((t&1)*32) : ((t&3)*16);
  const int wsb = (BN==128) ? ((t&1)*4)  : ((t&3)*2);

  uint4  war[WNL];
  uint4  aab[2];
  float4 aaf[4];

  auto loadA = [&](int k0){
    if constexpr (ABF16) {
      const u16* A = (const u16*)Av;
      aab[0] = *reinterpret_cast<const uint4*>(A + (size_t)(m0+arow)*512 + k0 + akc);
      aab[1] = *reinterpret_cast<const uint4*>(A + (size_t)(m0+arow)*512 + k0 + akc + 8);
    } else {
      const float* A = (const float*)Av;
      #pragma unroll
      for (int q = 0; q < 4; ++q)
        aaf[q] = *reinterpret_cast<const float4*>(A + (size_t)(m0+arow)*512 + k0 + akc + 4*q);
    }
  };
  auto loadW = [&](int k0){
    #pragma unroll
    for (int i = 0; i < WNL; ++i)
      war[i] = *reinterpret_cast<const uint4*>(WT + (size_t)(n0+wrn)*512 + k0 + wkc + 8*i);
  };
  auto writeA = [&](int bf){
    uint4 v0, v1;
    if constexpr (ABF16) { v0 = aab[0]; v1 = aab[1]; }
    else {
      v0.x = pack2(aaf[0].x, aaf[0].y); v0.y = pack2(aaf[0].z, aaf[0].w);
      v0.z = pack2(aaf[1].x, aaf[1].y); v0.w = pack2(aaf[1].z, aaf[1].w);
      v1.x = pack2(aaf[2].x, aaf[2].y); v1.y = pack2(aaf[2].z, aaf[2].w);
      v1.z = pack2(aaf[3].x, aaf[3].y); v1.w = pack2(aaf[3].z, aaf[3].w);
    }
    *reinterpret_cast<uint4*>(&As[bf][arow*64 + (((as0  ) ^ (arow&7)) << 3)]) = v0;
    *reinterpret_cast<uint4*>(&As[bf][arow*64 + (((as0+1) ^ (arow&7)) << 3)]) = v1;
  };
  auto writeW = [&](int bf){
    #pragma unroll
    for (int i = 0; i < WNL; ++i)
      *reinterpret_cast<uint4*>(&Ws[bf][wrn*64 + (((wsb+i) ^ (wrn&7)) << 3)]) = war[i];
  };

  const f32x4 fz = {0.f,0.f,0.f,0.f};
  f32x4 acc[4][NI];
  #pragma unroll
  for (int mi = 0; mi < 4; ++mi)
    #pragma unroll
    for (int ni = 0; ni < NI; ++ni) acc[mi][ni] = fz;

  loadA(0); loadW(0);
  writeA(0); writeW(0);
  __syncthreads();

  for (int kt = 0; kt < 8; ++kt) {
    const int cur = kt & 1;
    if (kt < 7) { loadA((kt+1)*64); loadW((kt+1)*64); }
    #pragma unroll
    for (int ks = 0; ks < 2; ++ks) {
      short8 bfr[NI], afr[4];
      #pragma unroll
      for (int ni = 0; ni < NI; ++ni) {
        const int n = wn + 16*ni + r15;
        bfr[ni] = *reinterpret_cast<const short8*>(&Ws[cur][n*64 + (((ks*4+g) ^ (n&7)) << 3)]);
      }
      #pragma unroll
      for (int mi = 0; mi < 4; ++mi) {
        const int m = 16*mi + r15;
        afr[mi] = *reinterpret_cast<const short8*>(&As[cur][m*64 + (((ks*4+g) ^ (m&7)) << 3)]);
      }
      #pragma unroll
      for (int mi = 0; mi < 4; ++mi)
        #pragma unroll
        for (int ni = 0; ni < NI; ++ni)
          acc[mi][ni] = __builtin_amdgcn_mfma_f32_16x16x32_bf16(afr[mi], bfr[ni], acc[mi][ni], 0, 0, 0);
    }
    if (kt < 7) { writeA(cur^1); writeW(cur^1); }
    __syncthreads();
  }

  float bia[NI];
  #pragma unroll
  for (int ni = 0; ni < NI; ++ni) bia[ni] = bias[n0 + wn + 16*ni + r15];
  #pragma unroll
  for (int mi = 0; mi < 4; ++mi) {
    #pragma unroll
    for (int ni = 0; ni < NI; ++ni) {
      #pragma unroll
      for (int j = 0; j < 4; ++j) {
        const int row = m0 + 16*mi + 4*g + j;
        const int col = n0 + wn + 16*ni + r15;
        const float v = (acc[mi][ni][j] + bia[ni]) * scale;
        if constexpr (SCATTER) {
          const int bb = row & 1, ntok = row >> 1;
          const int h = col >> 6, c = col & 63;
          ((u16*)Cd)[(((size_t)(bb*8 + h) * NN + ntok) * 64) + c] = f2bf(v);
        } else if constexpr (OUTF32) {
          ((float*)Cd)[(size_t)row * 512 + col] = v;
        } else {
          ((u16*)Cd)[(size_t)row * 512 + col] = f2bf(v);
        }
      }
    }
  }
}

// Fused QKV projections: grid (64, 4, 3).
__global__ __launch_bounds__(256)
void gemm_qkv(const float* __restrict__ x0, const float* __restrict__ x1,
              const float* __restrict__ x2, const u16* __restrict__ WT3,
              const float* __restrict__ b0, const float* __restrict__ b1,
              const float* __restrict__ b2, u16* __restrict__ dst, float qscale)
{
  const int z = blockIdx.z;
  const float* A    = (z == 0) ? x0 : (z == 1) ? x1 : x2;
  const float* bias = (z == 0) ? b0 : (z == 1) ? b1 : b2;
  gemm_core<128, true, false, false>(A, WT3 + (size_t)z*262144, bias,
                                     dst + (size_t)z*2097152,
                                     (z == 0) ? qscale : 1.0f,
                                     blockIdx.x*64, blockIdx.y*128);
}

// Output projection: grid (64, 8).
__global__ __launch_bounds__(256)
void gemm_wo(const u16* __restrict__ Ob, const u16* __restrict__ WT,
             const float* __restrict__ bias, float* __restrict__ out)
{
  gemm_core<64, false, true, true>(Ob, WT, bias, out, 1.0f,
                                   blockIdx.x*64, blockIdx.y*64);
}

// MFMA flash attention, 8 waves / 128 q, split-K, exp2 domain, 1 barrier/tile.
// K via global_load_lds (pre-swizzled source); P through per-wave Ps LDS;
// defer-max; bf16 split-K partials; s_setprio around MFMA clusters (T5).
// Q pre-scaled by 0.125*log2e. Natural regalloc (r12: forcing 32 VGPR spilled).
__global__ __launch_bounds__(512)
void attn_mfma(const u16* __restrict__ Q, const u16* __restrict__ K,
               const u16* __restrict__ V, const u8* __restrict__ cmb,
               const float* __restrict__ mw, u16* __restrict__ O,
               u16* __restrict__ Opart, float2* __restrict__ Ml, int kspan)
{
  __shared__ u16 Ks[2][64*64];  // [key][ch] pre-swizzled (slot^(key&7) at source)
  __shared__ u16 Vs[2][64*64];  // [ch][key], key-slot(8) XOR (ch&7) XOR (ch>>3)
  __shared__ u16 Ps[8][16*64];  // per wave: [q][key], key-slot(8) XOR (q&7)
  __shared__ float lut[16];     // rel-bias (log2 units), -inf for padded

  const int t = threadIdx.x;
  const int lane = t & 63;
  const int w = t >> 6;
  const int g = lane >> 4;
  const int r15 = lane & 15;
  const int bh = blockIdx.y;
  const int z = blockIdx.z;
  const int b = bh >> 3, h = bh & 7;
  const int n0 = blockIdx.x * 128;
  const int nq = n0 + w*16 + r15;
  const int k_beg = z * kspan;
  const float NEGINF = -__builtin_inff();

  if (t < 16) {
    const float mw0 = mw[h*4+0], mw1 = mw[h*4+1], mw2 = mw[h*4+2];
    const float msc = mw[h*4+3];
    const float mxw = fmaxf(mw0, fmaxf(mw1, mw2));
    const float e0 = __expf(mw0-mxw), e1 = __expf(mw1-mxw), e2 = __expf(mw2-mxw);
    const float inv = msc / (e0+e1+e2);
    float v = ((t & 1) ? 0.f : e0*inv) + ((t & 2) ? 0.f : e1*inv)
            + ((t & 4) ? 0.f : e2*inv);
    lut[t] = (t & 8) ? NEGINF : v * LOG2E;
  }

  const u16* qrow = Q + ((size_t)bh*NN + nq)*64;
  const short8 bq0 = *reinterpret_cast<const short8*>(qrow + 8*g);
  const short8 bq1 = *reinterpret_cast<const short8*>(qrow + 32 + 8*g);

  const u8* crow = cmb + ((size_t)(b*NN + nq))*NN;
  const u16* Kbase = K + (size_t)bh*NN*64;
  const u16* Vbase = V + (size_t)bh*NN*64;

  float m_run = NEGINF, l_run = 0.f;
  const f32x4 fz = {0.f, 0.f, 0.f, 0.f};
  f32x4 oacc[4] = {fz, fz, fz, fz};

  const int sm  = t >> 3;                    // staging key row 0..63
  const int ssl = t & 7;                     // dest slot (linear in LDS)
  const int kcol = (ssl ^ (sm & 7)) * 8;     // pre-swizzled K source column
  const int sc0 = (t & 7) * 8;               // V source col base

  uint4 vreg;
  auto gloadK = [&](int m0, int bf){
    gload16(Kbase + (size_t)(m0 + sm)*64 + kcol, &Ks[bf][w*512 + (lane << 3)]);
  };
  auto loadV = [&](int m0){
    vreg = *reinterpret_cast<const uint4*>(Vbase + (size_t)(m0 + sm)*64 + sc0);
  };
  auto writeV = [&](int bf){
    u16 e[8];
    e[0]=vreg.x&0xffff; e[1]=vreg.x>>16; e[2]=vreg.y&0xffff; e[3]=vreg.y>>16;
    e[4]=vreg.z&0xffff; e[5]=vreg.z>>16; e[6]=vreg.w&0xffff; e[7]=vreg.w>>16;
    #pragma unroll
    for (int i = 0; i < 8; ++i) {
      const int c = sc0 + i;
      Vs[bf][c*64 + ((((sm>>3) ^ (c&7) ^ (c>>3)) << 3) | (sm & 7))] = e[i];
    }
  };

  const int ntiles = kspan >> 6;
  gloadK(k_beg, 0);
  loadV(k_beg);
  writeV(0);
  __syncthreads();   // drains vmcnt+lgkm; covers lut + buf0

  for (int it = 0; it < ntiles; ++it) {
    const int cur = it & 1;
    const int m0 = k_beg + it * 64;
    const bool more = (it + 1 < ntiles);
    if (more) { gloadK(m0 + 64, cur ^ 1); loadV(m0 + 64); }

    // S^T = K @ Q^T
    float sv[4][4];
    __builtin_amdgcn_s_setprio(1);
    #pragma unroll
    for (int kt = 0; kt < 4; ++kt) {
      const int key = 16*kt + r15;
      const short8 a0 = *reinterpret_cast<const short8*>(&Ks[cur][key*64 + (((g  ) ^ (key&7)) << 3)]);
      const short8 a1 = *reinterpret_cast<const short8*>(&Ks[cur][key*64 + (((g+4) ^ (key&7)) << 3)]);
      f32x4 s = fz;
      s = __builtin_amdgcn_mfma_f32_16x16x32_bf16(a0, bq0, s, 0, 0, 0);
      s = __builtin_amdgcn_mfma_f32_16x16x32_bf16(a1, bq1, s, 0, 0, 0);
      const u32 cw = *reinterpret_cast<const u32*>(crow + m0 + 16*kt + 4*g);
      #pragma unroll
      for (int j = 0; j < 4; ++j)
        sv[kt][j] = s[j] + lut[(cw >> (8*j)) & 0xfu];
    }
    __builtin_amdgcn_s_setprio(0);
    float pmax = NEGINF;
    #pragma unroll
    for (int kt = 0; kt < 4; ++kt)
      #pragma unroll
      for (int j = 0; j < 4; ++j) pmax = fmaxf(pmax, sv[kt][j]);
    float tmax = pmax;
    tmax = fmaxf(tmax, __shfl_xor(tmax, 16));
    tmax = fmaxf(tmax, __shfl_xor(tmax, 32));

    // defer-max: skip rescale when tile max doesn't grow past THR (wave-uniform)
    const bool skip = __all((m_run != NEGINF) && (tmax <= m_run + 10.0f));
    float nm = m_run, sc = 1.0f;
    if (!skip) {
      nm = fmaxf(m_run, tmax);
      if (nm != NEGINF) { sc = exp2f(m_run - nm); m_run = nm; }
      #pragma unroll
      for (int ct = 0; ct < 4; ++ct) oacc[ct] *= sc;
    }

    // P = exp2(S - m), write P^T (bf16) to per-wave Ps (wave-private; DS ops
    // in-order per wave -> no barrier needed before the bp reads)
    float psum = 0.f;
    #pragma unroll
    for (int kt = 0; kt < 4; ++kt) {
      float p[4];
      #pragma unroll
      for (int j = 0; j < 4; ++j) {
        p[j] = (nm == NEGINF) ? 0.f : exp2f(sv[kt][j] - nm);
        psum += p[j];
      }
      const int slot = 2*kt + (g >> 1);
      const int off  = 4 * (g & 1);
      *reinterpret_cast<ushort4*>(&Ps[w][r15*64 + ((slot ^ (r15 & 7)) << 3) + off]) =
        make_ushort4(f2bf(p[0]), f2bf(p[1]), f2bf(p[2]), f2bf(p[3]));
    }
    psum += __shfl_xor(psum, 16);
    psum += __shfl_xor(psum, 32);
    l_run = l_run * sc + psum;

    // O^T += V^T @ P^T
    const short8 bp0 = *reinterpret_cast<const short8*>(&Ps[w][r15*64 + (((g  ) ^ (r15 & 7)) << 3)]);
    const short8 bp1 = *reinterpret_cast<const short8*>(&Ps[w][r15*64 + (((g+4) ^ (r15 & 7)) << 3)]);
    __builtin_amdgcn_s_setprio(1);
    #pragma unroll
    for (int ct = 0; ct < 4; ++ct) {
      const int c = 16*ct + r15;
      const short8 av0 = *reinterpret_cast<const short8*>(
        &Vs[cur][c*64 + ((((g  ) ^ (c&7) ^ (c>>3))) << 3)]);
      const short8 av1 = *reinterpret_cast<const short8*>(
        &Vs[cur][c*64 + ((((g+4) ^ (c&7) ^ (c>>3))) << 3)]);
      oacc[ct] = __builtin_amdgcn_mfma_f32_16x16x32_bf16(av0, bp0, oacc[ct], 0, 0, 0);
      oacc[ct] = __builtin_amdgcn_mfma_f32_16x16x32_bf16(av1, bp1, oacc[ct], 0, 0, 0);
    }
    __builtin_amdgcn_s_setprio(0);

    if (more) writeV(cur ^ 1);
    __syncthreads();
  }

  if (Opart) {
    u16* orow = Opart + (((size_t)(z*16 + bh)) * NN + nq) * 64;
    #pragma unroll
    for (int ct = 0; ct < 4; ++ct)
      *reinterpret_cast<ushort4*>(orow + 16*ct + 4*g) =
        make_ushort4(f2bf(oacc[ct][0]), f2bf(oacc[ct][1]),
                     f2bf(oacc[ct][2]), f2bf(oacc[ct][3]));
    if (g == 0)
      Ml[((size_t)(z*16 + bh)) * NN + nq] = make_float2(m_run, l_run);
  } else {
    const float rinv = 1.f / l_run;
    #pragma unroll
    for (int ct = 0; ct < 4; ++ct) {
      u16* dst = O + ((size_t)(nq*2 + b))*512 + h*64 + 16*ct + 4*g;
      *reinterpret_cast<ushort4*>(dst) =
        make_ushort4(f2bf(oacc[ct][0]*rinv), f2bf(oacc[ct][1]*rinv),
                     f2bf(oacc[ct][2]*rinv), f2bf(oacc[ct][3]*rinv));
    }
  }
}

// Merge split-K partials (bf16 partials, log2-domain m). wave = (bh, q).
__global__ __launch_bounds__(256)
void combine_k(const u16* __restrict__ Opart, const float2* __restrict__ Ml,
               u16* __restrict__ Ob, int nsplit)
{
  const int t = threadIdx.x;
  const int lane = t & 63, w = t >> 6;
  const int q = blockIdx.x * 4 + w;
  const int bh = blockIdx.y;
  const int b = bh >> 3, h = bh & 7;

  float M = -__builtin_inff();
  for (int s = 0; s < nsplit; ++s)
    M = fmaxf(M, Ml[((size_t)(s*16 + bh)) * NN + q].x);

  float num = 0.f, den = 0.f;
  for (int s = 0; s < nsplit; ++s) {
    const float2 ml = Ml[((size_t)(s*16 + bh)) * NN + q];
    const float ws = (ml.x == -__builtin_inff()) ? 0.f : exp2f(ml.x - M);
    den += ws * ml.y;
    num += ws * bf1(Opart[(((size_t)(s*16 + bh)) * NN + q) * 64 + lane]);
  }
  const float r = (den > 0.f) ? num / den : 0.f;
  Ob[((size_t)(q*2 + b)) * 512 + h*64 + lane] = f2bf(r);
}

extern "C" void kernel_launch(void* const* d_in, const int* in_sizes, int n_in,
                              void* d_out, int out_size, void* d_ws, size_t ws_size,
                              hipStream_t stream)
{
  const float* xq = (const float*)d_in[0];
  const float* xk = (const float*)d_in[1];
  const float* xv = (const float*)d_in[2];
  const int*   am = (const int*)d_in[3];
  const int*   kp = (const int*)d_in[4];
  const float* Wq = (const float*)d_in[5];
  const float* bq = (const float*)d_in[6];
  const float* Wk = (const float*)d_in[7];
  const float* bk = (const float*)d_in[8];
  const float* Wv = (const float*)d_in[9];
  const float* bv = (const float*)d_in[10];
  const float* Wo = (const float*)d_in[11];
  const float* bo = (const float*)d_in[12];
  const float* mw = (const float*)d_in[13];

  u16* Qb = (u16*)d_ws;                       // [16][2048][64] bf16, 4 MB (x3 = QKV)
  u16* Kb = Qb + (size_t)16*NN*64;
  u16* Vb = Kb + (size_t)16*NN*64;
  u16* Ob = Vb + (size_t)16*NN*64;            // [4096][512] bf16, 4 MB
  u8*  cmb = (u8*)(Ob + (size_t)4096*512);    // [2][2048][2048] bytes, 8 MB
  u8*  R   = cmb + (size_t)2*NN*NN;           // scratch region

  u16* Opart = (u16*)R;                       // split-K bf16 partials (<= 17.75 MB @ nsplit=4)
  const size_t base_bytes = (size_t)(R - (u8*)d_ws);
  int nsplit = 1;
  for (int s = 4; s >= 1; s >>= 1) {
    const size_t need = base_bytes + (size_t)s * 16 * NN * (64*2 + 8);
    if (need <= ws_size) { nsplit = s; break; }
  }
  float2* Ml = (float2*)(Opart + (size_t)nsplit * 16 * NN * 64);
  const bool split = (base_bytes + (size_t)16*NN*(64*2+8) <= ws_size);

  // WT4 region at R + 18 MB — disjoint from Opart span; ws >= 59.6 MB
  // established (r16's selector picked nsplit=8). Defensive fallback below.
  u16* WT4 = (u16*)(R + (size_t)18*1024*1024);
  const bool wt4_ok = (base_bytes + (size_t)18*1024*1024 + 4*262144*2 <= ws_size);
  u16* WT3 = wt4_ok ? WT4 : (u16*)R;          // fallback: pre-attn alias (r15 layout)
  u16* WTo = wt4_ok ? (WT4 + 3*262144) : Qb;

  prep_k<<<(2*NN*NN/4 + 255)/256, 256, 0, stream>>>(am, kp, cmb);

  const float qscale = 0.125f * LOG2E;
  if (wt4_ok) {
    trw4_k<<<dim3(16, 16, 4), 256, 0, stream>>>(Wq, Wk, Wv, Wo, WT4);
  } else {
    trw4_k<<<dim3(16, 16, 3), 256, 0, stream>>>(Wq, Wk, Wv, Wo, WT3);
  }
  gemm_qkv<<<dim3(64, 4, 3), 256, 0, stream>>>(xq, xk, xv, WT3, bq, bk, bv, Qb, qscale);

  if (split) {
    attn_mfma<<<dim3(16, 16, nsplit), 512, 0, stream>>>(Qb, Kb, Vb, cmb, mw, Ob,
                                                        Opart, Ml, NN / nsplit);
    combine_k<<<dim3(NN/4, 16), 256, 0, stream>>>(Opart, Ml, Ob, nsplit);
  } else {
    attn_mfma<<<dim3(16, 16, 1), 512, 0, stream>>>(Qb, Kb, Vb, cmb, mw, Ob,
                                                   nullptr, nullptr, NN);
  }
  if (!wt4_ok)
    trw_k<<<dim3(16, 16), 256, 0, stream>>>(Wo, WTo);
  gemm_wo<<<dim3(64, 8), 256, 0, stream>>>(Ob, WTo, bo, (float*)d_out);
}

// Round 21
// 121.023 us; speedup vs baseline: 1.0821x; 1.0036x over previous
//
#include <hip/hip_runtime.h>
#include <hip/hip_bf16.h>

#define NN 2048
#define LOG2E 1.4426950408889634f

typedef unsigned int u32;
typedef unsigned short u16;
typedef unsigned char u8;

typedef __attribute__((ext_vector_type(8))) short short8;
typedef __attribute__((ext_vector_type(4))) float f32x4;

__device__ __forceinline__ u16 f2bf(float f){
  __hip_bfloat16 h = __float2bfloat16(f);
  return *reinterpret_cast<u16*>(&h);
}
__device__ __forceinline__ float bf1(u16 u){ return __uint_as_float(((u32)u) << 16); }
__device__ __forceinline__ u32 pack2(float a, float b){
  return (u32)f2bf(a) | ((u32)f2bf(b) << 16);
}
__device__ __forceinline__ void gload16(const void* g, void* l){
  __builtin_amdgcn_global_load_lds((const __attribute__((address_space(1))) u32*)g,
                                   (__attribute__((address_space(3))) u32*)l, 16, 0, 0);
}

// Transpose 4 W f32 [512][512] -> bf16 W^T [n][k]. grid (16,16,4).
__global__ __launch_bounds__(256)
void trw4_k(const float* __restrict__ W0, const float* __restrict__ W1,
            const float* __restrict__ W2, const float* __restrict__ W3,
            u16* __restrict__ WT)
{
  __shared__ float tile[32][33];
  const int zz = blockIdx.z;
  const float* W = (zz == 0) ? W0 : (zz == 1) ? W1 : (zz == 2) ? W2 : W3;
  u16* dst = WT + (size_t)zz * 262144;
  const int t = threadIdx.x;
  const int k0 = blockIdx.x * 32, n0 = blockIdx.y * 32;
  const int c = t & 31, r = t >> 5;
  #pragma unroll
  for (int i = 0; i < 4; ++i)
    tile[r + 8*i][c] = W[(size_t)(k0 + r + 8*i) * 512 + n0 + c];
  __syncthreads();
  #pragma unroll
  for (int i = 0; i < 4; ++i)
    dst[(size_t)(n0 + r + 8*i) * 512 + k0 + c] = f2bf(tile[c][r + 8*i]);
}

// Single-W transpose (fallback path only).
__global__ __launch_bounds__(256)
void trw_k(const float* __restrict__ W, u16* __restrict__ WT)
{
  __shared__ float tile[32][33];
  const int t = threadIdx.x;
  const int k0 = blockIdx.x * 32, n0 = blockIdx.y * 32;
  const int c = t & 31, r = t >> 5;
  #pragma unroll
  for (int i = 0; i < 4; ++i)
    tile[r + 8*i][c] = W[(size_t)(k0 + r + 8*i) * 512 + n0 + c];
  __syncthreads();
  #pragma unroll
  for (int i = 0; i < 4; ++i)
    WT[(size_t)(n0 + r + 8*i) * 512 + k0 + c] = f2bf(tile[c][r + 8*i]);
}

// Double-buffered MFMA GEMM core: C[64 x BN block] = (A @ W^T + bias)*scale.
template<int BN, bool SCATTER, bool ABF16, bool OUTF32>
__device__ __forceinline__
void gemm_core(const void* __restrict__ Av, const u16* __restrict__ WT,
               const float* __restrict__ bias, void* __restrict__ Cd,
               float scale, int m0, int n0)
{
  constexpr int NI  = BN / 64;
  constexpr int WNL = BN / 32;
  __shared__ u16 As[2][64*64];
  __shared__ u16 Ws[2][BN*64];

  const int t = threadIdx.x;
  const int lane = t & 63;
  const int w = t >> 6;
  const int g = lane >> 4, r15 = lane & 15;
  const int wn = w * (BN/4);

  const int arow = t >> 2, akc = (t & 3) * 16, as0 = (t & 3) * 2;
  const int wrn = (BN==128) ? (t>>1) : (t>>2);
  const int wkc = (BN==128) ? ((t&1)*32) : ((t&3)*16);
  const int wsb = (BN==128) ? ((t&1)*4)  : ((t&3)*2);

  uint4  war[WNL];
  uint4  aab[2];
  float4 aaf[4];

  auto loadA = [&](int k0){
    if constexpr (ABF16) {
      const u16* A = (const u16*)Av;
      aab[0] = *reinterpret_cast<const uint4*>(A + (size_t)(m0+arow)*512 + k0 + akc);
      aab[1] = *reinterpret_cast<const uint4*>(A + (size_t)(m0+arow)*512 + k0 + akc + 8);
    } else {
      const float* A = (const float*)Av;
      #pragma unroll
      for (int q = 0; q < 4; ++q)
        aaf[q] = *reinterpret_cast<const float4*>(A + (size_t)(m0+arow)*512 + k0 + akc + 4*q);
    }
  };
  auto loadW = [&](int k0){
    #pragma unroll
    for (int i = 0; i < WNL; ++i)
      war[i] = *reinterpret_cast<const uint4*>(WT + (size_t)(n0+wrn)*512 + k0 + wkc + 8*i);
  };
  auto writeA = [&](int bf){
    uint4 v0, v1;
    if constexpr (ABF16) { v0 = aab[0]; v1 = aab[1]; }
    else {
      v0.x = pack2(aaf[0].x, aaf[0].y); v0.y = pack2(aaf[0].z, aaf[0].w);
      v0.z = pack2(aaf[1].x, aaf[1].y); v0.w = pack2(aaf[1].z, aaf[1].w);
      v1.x = pack2(aaf[2].x, aaf[2].y); v1.y = pack2(aaf[2].z, aaf[2].w);
      v1.z = pack2(aaf[3].x, aaf[3].y); v1.w = pack2(aaf[3].z, aaf[3].w);
    }
    *reinterpret_cast<uint4*>(&As[bf][arow*64 + (((as0  ) ^ (arow&7)) << 3)]) = v0;
    *reinterpret_cast<uint4*>(&As[bf][arow*64 + (((as0+1) ^ (arow&7)) << 3)]) = v1;
  };
  auto writeW = [&](int bf){
    #pragma unroll
    for (int i = 0; i < WNL; ++i)
      *reinterpret_cast<uint4*>(&Ws[bf][wrn*64 + (((wsb+i) ^ (wrn&7)) << 3)]) = war[i];
  };

  const f32x4 fz = {0.f,0.f,0.f,0.f};
  f32x4 acc[4][NI];
  #pragma unroll
  for (int mi = 0; mi < 4; ++mi)
    #pragma unroll
    for (int ni = 0; ni < NI; ++ni) acc[mi][ni] = fz;

  loadA(0); loadW(0);
  writeA(0); writeW(0);
  __syncthreads();

  for (int kt = 0; kt < 8; ++kt) {
    const int cur = kt & 1;
    if (kt < 7) { loadA((kt+1)*64); loadW((kt+1)*64); }
    #pragma unroll
    for (int ks = 0; ks < 2; ++ks) {
      short8 bfr[NI], afr[4];
      #pragma unroll
      for (int ni = 0; ni < NI; ++ni) {
        const int n = wn + 16*ni + r15;
        bfr[ni] = *reinterpret_cast<const short8*>(&Ws[cur][n*64 + (((ks*4+g) ^ (n&7)) << 3)]);
      }
      #pragma unroll
      for (int mi = 0; mi < 4; ++mi) {
        const int m = 16*mi + r15;
        afr[mi] = *reinterpret_cast<const short8*>(&As[cur][m*64 + (((ks*4+g) ^ (m&7)) << 3)]);
      }
      #pragma unroll
      for (int mi = 0; mi < 4; ++mi)
        #pragma unroll
        for (int ni = 0; ni < NI; ++ni)
          acc[mi][ni] = __builtin_amdgcn_mfma_f32_16x16x32_bf16(afr[mi], bfr[ni], acc[mi][ni], 0, 0, 0);
    }
    if (kt < 7) { writeA(cur^1); writeW(cur^1); }
    __syncthreads();
  }

  float bia[NI];
  #pragma unroll
  for (int ni = 0; ni < NI; ++ni) bia[ni] = bias[n0 + wn + 16*ni + r15];
  #pragma unroll
  for (int mi = 0; mi < 4; ++mi) {
    #pragma unroll
    for (int ni = 0; ni < NI; ++ni) {
      #pragma unroll
      for (int j = 0; j < 4; ++j) {
        const int row = m0 + 16*mi + 4*g + j;
        const int col = n0 + wn + 16*ni + r15;
        const float v = (acc[mi][ni][j] + bia[ni]) * scale;
        if constexpr (SCATTER) {
          const int bb = row & 1, ntok = row >> 1;
          const int h = col >> 6, c = col & 63;
          ((u16*)Cd)[(((size_t)(bb*8 + h) * NN + ntok) * 64) + c] = f2bf(v);
        } else if constexpr (OUTF32) {
          ((float*)Cd)[(size_t)row * 512 + col] = v;
        } else {
          ((u16*)Cd)[(size_t)row * 512 + col] = f2bf(v);
        }
      }
    }
  }
}

// Merged front kernel: blocks [0,768) run QKV GEMM tiles (compute-bound),
// blocks [768, 768+8192) run mask prep (HBM-bound). The two roles are
// data-independent; co-residency overlaps the HBM stream with MFMA compute.
__global__ __launch_bounds__(256)
void front_k(const float* __restrict__ x0, const float* __restrict__ x1,
             const float* __restrict__ x2, const u16* __restrict__ WT3,
             const float* __restrict__ b0, const float* __restrict__ b1,
             const float* __restrict__ b2, u16* __restrict__ dst, float qscale,
             const int* __restrict__ am, const int* __restrict__ kp,
             u8* __restrict__ cmb)
{
  const int bid = blockIdx.x;
  if (bid < 768) {
    // QKV role: z = bid>>8, rem = bid&255 -> bx = rem&63 (m0), by = rem>>6 (n0)
    const int z  = bid >> 8;
    const int rem = bid & 255;
    const int bx = rem & 63, by = rem >> 6;
    const float* A    = (z == 0) ? x0 : (z == 1) ? x1 : x2;
    const float* bias = (z == 0) ? b0 : (z == 1) ? b1 : b2;
    gemm_core<128, true, false, false>(A, WT3 + (size_t)z*262144, bias,
                                       dst + (size_t)z*2097152,
                                       (z == 0) ? qscale : 1.0f,
                                       bx*64, by*128);
  } else {
    // prep role: combo byte per (b,n,m)
    const size_t tid  = (size_t)(bid - 768) * 256 + threadIdx.x;
    const size_t base = tid * 4;
    const int row = (int)(base >> 11);
    const int m0  = (int)(base & 2047);
    const int b = row >> 11, n = row & 2047;
    const size_t e0 = (((size_t)(b*3) * NN) + n) * NN + m0;
    const int4 a0 = *reinterpret_cast<const int4*>(am + e0);
    const int4 a1 = *reinterpret_cast<const int4*>(am + e0 + (size_t)NN*NN);
    const int4 a2 = *reinterpret_cast<const int4*>(am + e0 + 2*(size_t)NN*NN);
    const int4 kv = *reinterpret_cast<const int4*>(kp + (size_t)b*NN + m0);
    const int a0v[4] = {a0.x,a0.y,a0.z,a0.w};
    const int a1v[4] = {a1.x,a1.y,a1.z,a1.w};
    const int a2v[4] = {a2.x,a2.y,a2.z,a2.w};
    const int kvv[4] = {kv.x,kv.y,kv.z,kv.w};
    uchar4 out;
    u8* o = (u8*)&out;
    #pragma unroll
    for (int i = 0; i < 4; ++i)
      o[i] = (u8)((a0v[i]?1:0) | (a1v[i]?2:0) | (a2v[i]?4:0) | (kvv[i]?8:0));
    *reinterpret_cast<uchar4*>(cmb + base) = out;
  }
}

// Standalone prep (fallback path).
__global__ __launch_bounds__(256)
void prep_k(const int* __restrict__ am, const int* __restrict__ kp,
            u8* __restrict__ cmb)
{
  const size_t tid  = (size_t)blockIdx.x * 256 + threadIdx.x;
  const size_t base = tid * 4;
  const int row = (int)(base >> 11);
  const int m0  = (int)(base & 2047);
  const int b = row >> 11, n = row & 2047;
  const size_t e0 = (((size_t)(b*3) * NN) + n) * NN + m0;
  const int4 a0 = *reinterpret_cast<const int4*>(am + e0);
  const int4 a1 = *reinterpret_cast<const int4*>(am + e0 + (size_t)NN*NN);
  const int4 a2 = *reinterpret_cast<const int4*>(am + e0 + 2*(size_t)NN*NN);
  const int4 kv = *reinterpret_cast<const int4*>(kp + (size_t)b*NN + m0);
  const int a0v[4] = {a0.x,a0.y,a0.z,a0.w};
  const int a1v[4] = {a1.x,a1.y,a1.z,a1.w};
  const int a2v[4] = {a2.x,a2.y,a2.z,a2.w};
  const int kvv[4] = {kv.x,kv.y,kv.z,kv.w};
  uchar4 out;
  u8* o = (u8*)&out;
  #pragma unroll
  for (int i = 0; i < 4; ++i)
    o[i] = (u8)((a0v[i]?1:0) | (a1v[i]?2:0) | (a2v[i]?4:0) | (kvv[i]?8:0));
  *reinterpret_cast<uchar4*>(cmb + base) = out;
}

// Standalone QKV (fallback path).
__global__ __launch_bounds__(256)
void gemm_qkv(const float* __restrict__ x0, const float* __restrict__ x1,
              const float* __restrict__ x2, const u16* __restrict__ WT3,
              const float* __restrict__ b0, const float* __restrict__ b1,
              const float* __restrict__ b2, u16* __restrict__ dst, float qscale)
{
  const int z = blockIdx.z;
  const float* A    = (z == 0) ? x0 : (z == 1) ? x1 : x2;
  const float* bias = (z == 0) ? b0 : (z == 1) ? b1 : b2;
  gemm_core<128, true, false, false>(A, WT3 + (size_t)z*262144, bias,
                                     dst + (size_t)z*2097152,
                                     (z == 0) ? qscale : 1.0f,
                                     blockIdx.x*64, blockIdx.y*128);
}

// Output projection: grid (64, 8).
__global__ __launch_bounds__(256)
void gemm_wo(const u16* __restrict__ Ob, const u16* __restrict__ WT,
             const float* __restrict__ bias, float* __restrict__ out)
{
  gemm_core<64, false, true, true>(Ob, WT, bias, out, 1.0f,
                                   blockIdx.x*64, blockIdx.y*64);
}

// MFMA flash attention, 8 waves / 128 q, split-K, exp2 domain, 1 barrier/tile.
// K via global_load_lds (pre-swizzled source); P through per-wave Ps LDS;
// defer-max; bf16 split-K partials; s_setprio around MFMA clusters (T5).
// Q pre-scaled by 0.125*log2e. Natural regalloc (r12: forcing 32 VGPR spilled).
__global__ __launch_bounds__(512)
void attn_mfma(const u16* __restrict__ Q, const u16* __restrict__ K,
               const u16* __restrict__ V, const u8* __restrict__ cmb,
               const float* __restrict__ mw, u16* __restrict__ O,
               u16* __restrict__ Opart, float2* __restrict__ Ml, int kspan)
{
  __shared__ u16 Ks[2][64*64];  // [key][ch] pre-swizzled (slot^(key&7) at source)
  __shared__ u16 Vs[2][64*64];  // [ch][key], key-slot(8) XOR (ch&7) XOR (ch>>3)
  __shared__ u16 Ps[8][16*64];  // per wave: [q][key], key-slot(8) XOR (q&7)
  __shared__ float lut[16];     // rel-bias (log2 units), -inf for padded

  const int t = threadIdx.x;
  const int lane = t & 63;
  const int w = t >> 6;
  const int g = lane >> 4;
  const int r15 = lane & 15;
  const int bh = blockIdx.y;
  const int z = blockIdx.z;
  const int b = bh >> 3, h = bh & 7;
  const int n0 = blockIdx.x * 128;
  const int nq = n0 + w*16 + r15;
  const int k_beg = z * kspan;
  const float NEGINF = -__builtin_inff();

  if (t < 16) {
    const float mw0 = mw[h*4+0], mw1 = mw[h*4+1], mw2 = mw[h*4+2];
    const float msc = mw[h*4+3];
    const float mxw = fmaxf(mw0, fmaxf(mw1, mw2));
    const float e0 = __expf(mw0-mxw), e1 = __expf(mw1-mxw), e2 = __expf(mw2-mxw);
    const float inv = msc / (e0+e1+e2);
    float v = ((t & 1) ? 0.f : e0*inv) + ((t & 2) ? 0.f : e1*inv)
            + ((t & 4) ? 0.f : e2*inv);
    lut[t] = (t & 8) ? NEGINF : v * LOG2E;
  }

  const u16* qrow = Q + ((size_t)bh*NN + nq)*64;
  const short8 bq0 = *reinterpret_cast<const short8*>(qrow + 8*g);
  const short8 bq1 = *reinterpret_cast<const short8*>(qrow + 32 + 8*g);

  const u8* crow = cmb + ((size_t)(b*NN + nq))*NN;
  const u16* Kbase = K + (size_t)bh*NN*64;
  const u16* Vbase = V + (size_t)bh*NN*64;

  float m_run = NEGINF, l_run = 0.f;
  const f32x4 fz = {0.f, 0.f, 0.f, 0.f};
  f32x4 oacc[4] = {fz, fz, fz, fz};

  const int sm  = t >> 3;                    // staging key row 0..63
  const int ssl = t & 7;                     // dest slot (linear in LDS)
  const int kcol = (ssl ^ (sm & 7)) * 8;     // pre-swizzled K source column
  const int sc0 = (t & 7) * 8;               // V source col base

  uint4 vreg;
  auto gloadK = [&](int m0, int bf){
    gload16(Kbase + (size_t)(m0 + sm)*64 + kcol, &Ks[bf][w*512 + (lane << 3)]);
  };
  auto loadV = [&](int m0){
    vreg = *reinterpret_cast<const uint4*>(Vbase + (size_t)(m0 + sm)*64 + sc0);
  };
  auto writeV = [&](int bf){
    u16 e[8];
    e[0]=vreg.x&0xffff; e[1]=vreg.x>>16; e[2]=vreg.y&0xffff; e[3]=vreg.y>>16;
    e[4]=vreg.z&0xffff; e[5]=vreg.z>>16; e[6]=vreg.w&0xffff; e[7]=vreg.w>>16;
    #pragma unroll
    for (int i = 0; i < 8; ++i) {
      const int c = sc0 + i;
      Vs[bf][c*64 + ((((sm>>3) ^ (c&7) ^ (c>>3)) << 3) | (sm & 7))] = e[i];
    }
  };

  const int ntiles = kspan >> 6;
  gloadK(k_beg, 0);
  loadV(k_beg);
  writeV(0);
  __syncthreads();   // drains vmcnt+lgkm; covers lut + buf0

  for (int it = 0; it < ntiles; ++it) {
    const int cur = it & 1;
    const int m0 = k_beg + it * 64;
    const bool more = (it + 1 < ntiles);
    if (more) { gloadK(m0 + 64, cur ^ 1); loadV(m0 + 64); }

    // S^T = K @ Q^T
    float sv[4][4];
    __builtin_amdgcn_s_setprio(1);
    #pragma unroll
    for (int kt = 0; kt < 4; ++kt) {
      const int key = 16*kt + r15;
      const short8 a0 = *reinterpret_cast<const short8*>(&Ks[cur][key*64 + (((g  ) ^ (key&7)) << 3)]);
      const short8 a1 = *reinterpret_cast<const short8*>(&Ks[cur][key*64 + (((g+4) ^ (key&7)) << 3)]);
      f32x4 s = fz;
      s = __builtin_amdgcn_mfma_f32_16x16x32_bf16(a0, bq0, s, 0, 0, 0);
      s = __builtin_amdgcn_mfma_f32_16x16x32_bf16(a1, bq1, s, 0, 0, 0);
      const u32 cw = *reinterpret_cast<const u32*>(crow + m0 + 16*kt + 4*g);
      #pragma unroll
      for (int j = 0; j < 4; ++j)
        sv[kt][j] = s[j] + lut[(cw >> (8*j)) & 0xfu];
    }
    __builtin_amdgcn_s_setprio(0);
    float pmax = NEGINF;
    #pragma unroll
    for (int kt = 0; kt < 4; ++kt)
      #pragma unroll
      for (int j = 0; j < 4; ++j) pmax = fmaxf(pmax, sv[kt][j]);
    float tmax = pmax;
    tmax = fmaxf(tmax, __shfl_xor(tmax, 16));
    tmax = fmaxf(tmax, __shfl_xor(tmax, 32));

    // defer-max: skip rescale when tile max doesn't grow past THR (wave-uniform)
    const bool skip = __all((m_run != NEGINF) && (tmax <= m_run + 10.0f));
    float nm = m_run, sc = 1.0f;
    if (!skip) {
      nm = fmaxf(m_run, tmax);
      if (nm != NEGINF) { sc = exp2f(m_run - nm); m_run = nm; }
      #pragma unroll
      for (int ct = 0; ct < 4; ++ct) oacc[ct] *= sc;
    }

    // P = exp2(S - m), write P^T (bf16) to per-wave Ps (wave-private; DS ops
    // in-order per wave -> no barrier needed before the bp reads)
    float psum = 0.f;
    #pragma unroll
    for (int kt = 0; kt < 4; ++kt) {
      float p[4];
      #pragma unroll
      for (int j = 0; j < 4; ++j) {
        p[j] = (nm == NEGINF) ? 0.f : exp2f(sv[kt][j] - nm);
        psum += p[j];
      }
      const int slot = 2*kt + (g >> 1);
      const int off  = 4 * (g & 1);
      *reinterpret_cast<ushort4*>(&Ps[w][r15*64 + ((slot ^ (r15 & 7)) << 3) + off]) =
        make_ushort4(f2bf(p[0]), f2bf(p[1]), f2bf(p[2]), f2bf(p[3]));
    }
    psum += __shfl_xor(psum, 16);
    psum += __shfl_xor(psum, 32);
    l_run = l_run * sc + psum;

    // O^T += V^T @ P^T
    const short8 bp0 = *reinterpret_cast<const short8*>(&Ps[w][r15*64 + (((g  ) ^ (r15 & 7)) << 3)]);
    const short8 bp1 = *reinterpret_cast<const short8*>(&Ps[w][r15*64 + (((g+4) ^ (r15 & 7)) << 3)]);
    __builtin_amdgcn_s_setprio(1);
    #pragma unroll
    for (int ct = 0; ct < 4; ++ct) {
      const int c = 16*ct + r15;
      const short8 av0 = *reinterpret_cast<const short8*>(
        &Vs[cur][c*64 + ((((g  ) ^ (c&7) ^ (c>>3))) << 3)]);
      const short8 av1 = *reinterpret_cast<const short8*>(
        &Vs[cur][c*64 + ((((g+4) ^ (c&7) ^ (c>>3))) << 3)]);
      oacc[ct] = __builtin_amdgcn_mfma_f32_16x16x32_bf16(av0, bp0, oacc[ct], 0, 0, 0);
      oacc[ct] = __builtin_amdgcn_mfma_f32_16x16x32_bf16(av1, bp1, oacc[ct], 0, 0, 0);
    }
    __builtin_amdgcn_s_setprio(0);

    if (more) writeV(cur ^ 1);
    __syncthreads();
  }

  if (Opart) {
    u16* orow = Opart + (((size_t)(z*16 + bh)) * NN + nq) * 64;
    #pragma unroll
    for (int ct = 0; ct < 4; ++ct)
      *reinterpret_cast<ushort4*>(orow + 16*ct + 4*g) =
        make_ushort4(f2bf(oacc[ct][0]), f2bf(oacc[ct][1]),
                     f2bf(oacc[ct][2]), f2bf(oacc[ct][3]));
    if (g == 0)
      Ml[((size_t)(z*16 + bh)) * NN + nq] = make_float2(m_run, l_run);
  } else {
    const float rinv = 1.f / l_run;
    #pragma unroll
    for (int ct = 0; ct < 4; ++ct) {
      u16* dst = O + ((size_t)(nq*2 + b))*512 + h*64 + 16*ct + 4*g;
      *reinterpret_cast<ushort4*>(dst) =
        make_ushort4(f2bf(oacc[ct][0]*rinv), f2bf(oacc[ct][1]*rinv),
                     f2bf(oacc[ct][2]*rinv), f2bf(oacc[ct][3]*rinv));
    }
  }
}

// Merge split-K partials (bf16 partials, log2-domain m). wave = (bh, q).
__global__ __launch_bounds__(256)
void combine_k(const u16* __restrict__ Opart, const float2* __restrict__ Ml,
               u16* __restrict__ Ob, int nsplit)
{
  const int t = threadIdx.x;
  const int lane = t & 63, w = t >> 6;
  const int q = blockIdx.x * 4 + w;
  const int bh = blockIdx.y;
  const int b = bh >> 3, h = bh & 7;

  float M = -__builtin_inff();
  for (int s = 0; s < nsplit; ++s)
    M = fmaxf(M, Ml[((size_t)(s*16 + bh)) * NN + q].x);

  float num = 0.f, den = 0.f;
  for (int s = 0; s < nsplit; ++s) {
    const float2 ml = Ml[((size_t)(s*16 + bh)) * NN + q];
    const float ws = (ml.x == -__builtin_inff()) ? 0.f : exp2f(ml.x - M);
    den += ws * ml.y;
    num += ws * bf1(Opart[(((size_t)(s*16 + bh)) * NN + q) * 64 + lane]);
  }
  const float r = (den > 0.f) ? num / den : 0.f;
  Ob[((size_t)(q*2 + b)) * 512 + h*64 + lane] = f2bf(r);
}

extern "C" void kernel_launch(void* const* d_in, const int* in_sizes, int n_in,
                              void* d_out, int out_size, void* d_ws, size_t ws_size,
                              hipStream_t stream)
{
  const float* xq = (const float*)d_in[0];
  const float* xk = (const float*)d_in[1];
  const float* xv = (const float*)d_in[2];
  const int*   am = (const int*)d_in[3];
  const int*   kp = (const int*)d_in[4];
  const float* Wq = (const float*)d_in[5];
  const float* bq = (const float*)d_in[6];
  const float* Wk = (const float*)d_in[7];
  const float* bk = (const float*)d_in[8];
  const float* Wv = (const float*)d_in[9];
  const float* bv = (const float*)d_in[10];
  const float* Wo = (const float*)d_in[11];
  const float* bo = (const float*)d_in[12];
  const float* mw = (const float*)d_in[13];

  u16* Qb = (u16*)d_ws;                       // [16][2048][64] bf16, 4 MB (x3 = QKV)
  u16* Kb = Qb + (size_t)16*NN*64;
  u16* Vb = Kb + (size_t)16*NN*64;
  u16* Ob = Vb + (size_t)16*NN*64;            // [4096][512] bf16, 4 MB
  u8*  cmb = (u8*)(Ob + (size_t)4096*512);    // [2][2048][2048] bytes, 8 MB
  u8*  R   = cmb + (size_t)2*NN*NN;           // scratch region

  u16* Opart = (u16*)R;                       // split-K bf16 partials (<= 17.75 MB @ 4)
  const size_t base_bytes = (size_t)(R - (u8*)d_ws);
  int nsplit = 1;
  for (int s = 4; s >= 1; s >>= 1) {
    const size_t need = base_bytes + (size_t)s * 16 * NN * (64*2 + 8);
    if (need <= ws_size) { nsplit = s; break; }
  }
  float2* Ml = (float2*)(Opart + (size_t)nsplit * 16 * NN * 64);
  const bool split = (base_bytes + (size_t)16*NN*(64*2+8) <= ws_size);

  u16* WT4 = (u16*)(R + (size_t)18*1024*1024);
  const bool wt4_ok = (base_bytes + (size_t)18*1024*1024 + 4*262144*2 <= ws_size);
  u16* WT3 = wt4_ok ? WT4 : (u16*)R;
  u16* WTo = wt4_ok ? (WT4 + 3*262144) : Qb;

  const float qscale = 0.125f * LOG2E;
  trw4_k<<<dim3(16, 16, wt4_ok ? 4 : 3), 256, 0, stream>>>(Wq, Wk, Wv, Wo,
                                                           wt4_ok ? WT4 : WT3);
  // merged front: 768 qkv blocks + 8192 prep blocks (independent roles)
  front_k<<<dim3(768 + 8192), 256, 0, stream>>>(xq, xk, xv, WT3, bq, bk, bv, Qb,
                                                qscale, am, kp, cmb);

  if (split) {
    attn_mfma<<<dim3(16, 16, nsplit), 512, 0, stream>>>(Qb, Kb, Vb, cmb, mw, Ob,
                                                        Opart, Ml, NN / nsplit);
    combine_k<<<dim3(NN/4, 16), 256, 0, stream>>>(Opart, Ml, Ob, nsplit);
  } else {
    attn_mfma<<<dim3(16, 16, 1), 512, 0, stream>>>(Qb, Kb, Vb, cmb, mw, Ob,
                                                   nullptr, nullptr, NN);
  }
  if (!wt4_ok)
    trw_k<<<dim3(16, 16), 256, 0, stream>>>(Wo, WTo);
  gemm_wo<<<dim3(64, 8), 256, 0, stream>>>(Ob, WTo, bo, (float*)d_out);
}